// Round 6
// baseline (337.040 us; speedup 1.0000x reference)
//
#include <hip/hip_runtime.h>
#include <math.h>

#define BB 8
#define CC 64
#define NN 2048
#define KK 20
#define OO 128
#define CANDT 40
#define NPART 1024
#define M_TOT 327680.0f   // B*N*K

typedef __attribute__((ext_vector_type(8))) __bf16 bf8v;
typedef __attribute__((ext_vector_type(4))) float f32x4;

// ---------------------------------------------------------------------------
// k_pqprep (Path A): P/Q GEMMs + bf16 xT rows + f32 xTf rows + xx/xxf norms.
// ---------------------------------------------------------------------------
__global__ __launch_bounds__(256) void k_pqprep(const float* __restrict__ x,
                                                const float* __restrict__ W,
                                                float* __restrict__ P,
                                                float* __restrict__ Q,
                                                ushort* __restrict__ xT,
                                                float* __restrict__ xTf,
                                                double* __restrict__ xx,
                                                float* __restrict__ xxf) {
  __shared__ float tile[64][OO + 1];               // 33KB
  const int t = threadIdx.x;
  const int jj = t & 63, og = t >> 6;
  const int pt0 = blockIdx.x * 64;
  const int b = pt0 >> 11;
  const int jn = (pt0 & (NN - 1)) + jj;

  float xcol[CC];
#pragma unroll
  for (int c = 0; c < CC; ++c) xcol[c] = x[((size_t)(b * CC + c) << 11) + jn];

  if (og == 0) {                                   // prep outputs (wave 0)
    int i = pt0 + jj;
    ushort* rowp = xT + (size_t)i * CC;
    float* rowf = xTf + (size_t)i * CC;
    double s = 0.0;
#pragma unroll
    for (int c8 = 0; c8 < 8; ++c8) {
      unsigned tmp[8];
#pragma unroll
      for (int e = 0; e < 8; ++e) {
        float v = xcol[c8 * 8 + e];
        double dv = (double)v; s = fma(dv, dv, s);
        __bf16 h = (__bf16)v;
        ushort us; __builtin_memcpy(&us, &h, 2);
        tmp[e] = us;
      }
      uint4 pk;
      pk.x = tmp[0] | (tmp[1] << 16);
      pk.y = tmp[2] | (tmp[3] << 16);
      pk.z = tmp[4] | (tmp[5] << 16);
      pk.w = tmp[6] | (tmp[7] << 16);
      *(uint4*)(rowp + c8 * 8) = pk;
      *(float4*)(rowf + c8 * 8)     = make_float4(xcol[c8*8], xcol[c8*8+1], xcol[c8*8+2], xcol[c8*8+3]);
      *(float4*)(rowf + c8 * 8 + 4) = make_float4(xcol[c8*8+4], xcol[c8*8+5], xcol[c8*8+6], xcol[c8*8+7]);
    }
    xx[i] = s;
    xxf[i] = (float)s;
  }

  for (int oo = 0; oo < 32; ++oo) {
    int o = og * 32 + oo;
    const float* wr = W + (size_t)o * (2 * CC);
    float sp = 0.f;
#pragma unroll
    for (int c = 0; c < CC; ++c) sp = fmaf(wr[c], xcol[c], sp);
    tile[jj][o] = sp;
  }
  __syncthreads();
  for (int it = 0; it < 32; ++it) {
    int r = it * 2 + (t >> 7);
    P[((size_t)(pt0 + r)) * OO + (t & 127)] = tile[r][t & 127];
  }
  __syncthreads();
  for (int oo = 0; oo < 32; ++oo) {
    int o = og * 32 + oo;
    const float* wr = W + (size_t)o * (2 * CC);
    float sq = 0.f;
#pragma unroll
    for (int c = 0; c < CC; ++c) sq = fmaf(wr[CC + c] - wr[c], xcol[c], sq);
    tile[jj][o] = sq;
  }
  __syncthreads();
  for (int it = 0; it < 32; ++it) {
    int r = it * 2 + (t >> 7);
    Q[((size_t)(pt0 + r)) * OO + (t & 127)] = tile[r][t & 127];
  }
}

// ---------------------------------------------------------------------------
// k_prep (Path B fallback): standalone prep pass.
// ---------------------------------------------------------------------------
__global__ __launch_bounds__(256) void k_prep(const float* __restrict__ x,
                                              ushort* __restrict__ xT,
                                              float* __restrict__ xTf,
                                              double* __restrict__ xx,
                                              float* __restrict__ xxf) {
  int i = blockIdx.x * 256 + threadIdx.x;
  int b = i >> 11, n = i & (NN - 1);
  const float* p = x + ((size_t)b * CC) * NN + n;
  ushort* rowp = xT + (size_t)i * CC;
  float* rowf = xTf + (size_t)i * CC;
  double s = 0.0;
#pragma unroll
  for (int c8 = 0; c8 < 8; ++c8) {
    float f[8];
    unsigned tmp[8];
#pragma unroll
    for (int e = 0; e < 8; ++e) {
      float v = p[(size_t)(c8 * 8 + e) * NN];
      f[e] = v;
      double dv = (double)v; s = fma(dv, dv, s);
      __bf16 h = (__bf16)v;
      ushort us; __builtin_memcpy(&us, &h, 2);
      tmp[e] = us;
    }
    uint4 pk;
    pk.x = tmp[0] | (tmp[1] << 16);
    pk.y = tmp[2] | (tmp[3] << 16);
    pk.z = tmp[4] | (tmp[5] << 16);
    pk.w = tmp[6] | (tmp[7] << 16);
    *(uint4*)(rowp + c8 * 8) = pk;
    *(float4*)(rowf + c8 * 8)     = make_float4(f[0], f[1], f[2], f[3]);
    *(float4*)(rowf + c8 * 8 + 4) = make_float4(f[4], f[5], f[6], f[7]);
  }
  xx[i] = s;
  xxf[i] = (float)s;
}

// ---------------------------------------------------------------------------
// k_pq (Path B fallback): P/Q GEMMs only.
// ---------------------------------------------------------------------------
__global__ __launch_bounds__(256) void k_pq(const float* __restrict__ x,
                                            const float* __restrict__ W,
                                            float* __restrict__ P,
                                            float* __restrict__ Q) {
  __shared__ float tile[64][OO + 1];
  const int t = threadIdx.x;
  const int jj = t & 63, og = t >> 6;
  const int pt0 = blockIdx.x * 64;
  const int b = pt0 >> 11;
  const int jn = (pt0 & (NN - 1)) + jj;

  float xcol[CC];
#pragma unroll
  for (int c = 0; c < CC; ++c) xcol[c] = x[((size_t)(b * CC + c) << 11) + jn];

  for (int oo = 0; oo < 32; ++oo) {
    int o = og * 32 + oo;
    const float* wr = W + (size_t)o * (2 * CC);
    float sp = 0.f;
#pragma unroll
    for (int c = 0; c < CC; ++c) sp = fmaf(wr[c], xcol[c], sp);
    tile[jj][o] = sp;
  }
  __syncthreads();
  for (int it = 0; it < 32; ++it) {
    int r = it * 2 + (t >> 7);
    P[((size_t)(pt0 + r)) * OO + (t & 127)] = tile[r][t & 127];
  }
  __syncthreads();
  for (int oo = 0; oo < 32; ++oo) {
    int o = og * 32 + oo;
    const float* wr = W + (size_t)o * (2 * CC);
    float sq = 0.f;
#pragma unroll
    for (int c = 0; c < CC; ++c) sq = fmaf(wr[CC + c] - wr[c], xcol[c], sq);
    tile[jj][o] = sq;
  }
  __syncthreads();
  for (int it = 0; it < 32; ++it) {
    int r = it * 2 + (t >> 7);
    Q[((size_t)(pt0 + r)) * OO + (t & 127)] = tile[r][t & 127];
  }
}

// ---------------------------------------------------------------------------
// k_knn: 16-row tiles, 1024 thr (16 waves), 1 row per wave in selection.
// launch_bounds (1024,4): R5's (1024,8) forced VGPR=32 -> 42MB scratch spill
// (WRITE_SIZE evidence). Phase C re-reads keys from LDS instead of keeping a
// 16-reg key array, to stay under 64 VGPR for 8 waves/SIMD.
// ---------------------------------------------------------------------------
__global__ __launch_bounds__(1024, 4) void k_knn(
    const ushort* __restrict__ xT, const float* __restrict__ xxf,
    const float* __restrict__ xTf, const double* __restrict__ xx,
    int* __restrict__ idx) {
  extern __shared__ char smem[];
  ushort (*Sb)[NN] = (ushort(*)[NN])smem;          // [16][2048] = 64 KB
  int* Cj = (int*)(smem + 16 * NN * 2);            // [16][64] = 4 KB
  double* Sd = (double*)(smem + 16 * NN * 2 + 4096); // [16][64] = 8 KB
  const int t = threadIdx.x;
  const int w = t >> 6, lane = t & 63;
  const int bidswz = ((blockIdx.x & 7) << 7) + (blockIdx.x >> 3); // batch/XCD
  const int b = bidswz >> 7;
  const int i0 = (bidswz & 127) << 4;
  const int lr16 = lane & 15, kg = lane >> 4;
  const ushort* xTb = xT + (((size_t)b) << 11) * CC;

  // ---- Phase A: MFMA ----
  f32x4 acc[8];
#pragma unroll
  for (int ct = 0; ct < 8; ++ct)
#pragma unroll
    for (int q = 0; q < 4; ++q) acc[ct][q] = 0.f;

  const ushort* Arow = xTb + (size_t)(i0 + lr16) * CC + kg * 8;
  bf8v aF0 = *(const bf8v*)(Arow);
  bf8v aF1 = *(const bf8v*)(Arow + 32);
  const int j0w = w << 7;
#pragma unroll
  for (int ct = 0; ct < 8; ++ct) {
    const ushort* Brow = xTb + (size_t)(j0w + ct * 16 + lr16) * CC + kg * 8;
    bf8v bF0 = *(const bf8v*)(Brow);
    bf8v bF1 = *(const bf8v*)(Brow + 32);
    acc[ct] = __builtin_amdgcn_mfma_f32_16x16x32_bf16(aF0, bF0, acc[ct], 0, 0, 0);
    acc[ct] = __builtin_amdgcn_mfma_f32_16x16x32_bf16(aF1, bF1, acc[ct], 0, 0, 0);
  }

  // ---- Phase B: scores -> bf16 LDS ----
  const float* xxfb = xxf + (b << 11);
#pragma unroll
  for (int ct = 0; ct < 8; ++ct) {
    int j = j0w + ct * 16 + lr16;
    float xv = xxfb[j];
#pragma unroll
    for (int q = 0; q < 4; ++q) {
      int rr = kg * 4 + q;                         // C/D: col=lane&15, row=(lane>>4)*4+q (m89)
      float sv = 2.f * acc[ct][q] - xv;
      __bf16 hb = (__bf16)sv;
      ushort us; __builtin_memcpy(&us, &hb, 2);
      Sb[rr][j] = us;
    }
  }
  __syncthreads();

  // ---- Phase C: wave w owns row i0+w ----
  const int irow = i0 + w;
  // pass 1: per-lane top-4 values (monotone u16 keys), keys NOT kept in regs
  unsigned t0 = 0, t1 = 0, t2 = 0, t3 = 0;
#pragma unroll
  for (int g = 0; g < 16; ++g) {
    unsigned raw = *(const unsigned*)(&Sb[w][lane * 2 + g * 128]);
    unsigned r0 = raw & 0xffffu, r1 = raw >> 16;
    unsigned k0 = r0 ^ (0x8000u | ((r0 >> 15) * 0x7FFFu));  // monotone u16
    unsigned k1 = r1 ^ (0x8000u | ((r1 >> 15) * 0x7FFFu));
    unsigned mx, mn;
    mx = k0 > t0 ? k0 : t0; mn = k0 > t0 ? t0 : k0; t0 = mx;
    mx = mn > t1 ? mn : t1; mn = mn > t1 ? t1 : mn; t1 = mx;
    mx = mn > t2 ? mn : t2; mn = mn > t2 ? t2 : mn; t2 = mx;
    t3 = mn > t3 ? mn : t3;
    mx = k1 > t0 ? k1 : t0; mn = k1 > t0 ? t0 : k1; t0 = mx;
    mx = mn > t1 ? mn : t1; mn = mn > t1 ? t1 : mn; t1 = mx;
    mx = mn > t2 ? mn : t2; mn = mn > t2 ? t2 : mn; t2 = mx;
    t3 = mn > t3 ? mn : t3;
  }
  // MSB radix with capped (top-4) ballot counts -> tau ~ 40th largest
  unsigned tau = 0;
  for (int bit = 15; bit >= 0; --bit) {
    unsigned cnd = tau | (1u << bit);
    int tot = __popcll(__ballot(t0 >= cnd)) + __popcll(__ballot(t1 >= cnd)) +
              __popcll(__ballot(t2 >= cnd)) + __popcll(__ballot(t3 >= cnd));
    if (tot >= CANDT) tau = cnd;
  }
  // pass 2: hit mask (re-read LDS), exact count, prefix scan
  unsigned mask = 0;
#pragma unroll
  for (int g = 0; g < 16; ++g) {
    unsigned raw = *(const unsigned*)(&Sb[w][lane * 2 + g * 128]);
    unsigned r0 = raw & 0xffffu, r1 = raw >> 16;
    unsigned k0 = r0 ^ (0x8000u | ((r0 >> 15) * 0x7FFFu));
    unsigned k1 = r1 ^ (0x8000u | ((r1 >> 15) * 0x7FFFu));
    mask |= (k0 >= tau ? 1u : 0u) << (2 * g);
    mask |= (k1 >= tau ? 1u : 0u) << (2 * g + 1);
  }
  int myc = __popc(mask);
  int pre = myc;
#pragma unroll
  for (int off = 1; off < 64; off <<= 1) {
    int o = __shfl_up(pre, off, 64);
    pre += (lane >= off) ? o : 0;
  }
  int tot = __shfl(pre, 63, 64);
  if (tot > 64) {                                  // cold exact-radix fallback
    tau = 0;
    for (int bit = 15; bit >= 0; --bit) {
      unsigned cnd = tau | (1u << bit);
      int cc = 0;
#pragma unroll
      for (int g = 0; g < 16; ++g) {
        unsigned raw = *(const unsigned*)(&Sb[w][lane * 2 + g * 128]);
        unsigned r0 = raw & 0xffffu, r1 = raw >> 16;
        cc += ((r0 ^ (0x8000u | ((r0 >> 15) * 0x7FFFu))) >= cnd) ? 1 : 0;
        cc += ((r1 ^ (0x8000u | ((r1 >> 15) * 0x7FFFu))) >= cnd) ? 1 : 0;
      }
#pragma unroll
      for (int off = 1; off < 64; off <<= 1) cc += __shfl_xor(cc, off, 64);
      if (cc >= CANDT) tau = cnd;
    }
    mask = 0;
#pragma unroll
    for (int g = 0; g < 16; ++g) {
      unsigned raw = *(const unsigned*)(&Sb[w][lane * 2 + g * 128]);
      unsigned r0 = raw & 0xffffu, r1 = raw >> 16;
      unsigned k0 = r0 ^ (0x8000u | ((r0 >> 15) * 0x7FFFu));
      unsigned k1 = r1 ^ (0x8000u | ((r1 >> 15) * 0x7FFFu));
      mask |= (k0 >= tau ? 1u : 0u) << (2 * g);
      mask |= (k1 >= tau ? 1u : 0u) << (2 * g + 1);
    }
    myc = __popc(mask);
    pre = myc;
#pragma unroll
    for (int off = 1; off < 64; off <<= 1) {
      int o = __shfl_up(pre, off, 64);
      pre += (lane >= off) ? o : 0;
    }
    tot = __shfl(pre, 63, 64);
  }
  // bitmask compaction
  {
    int slot = pre - myc;
    unsigned m2 = mask;
    while (m2) {
      int bp = __builtin_ctz(m2); m2 &= m2 - 1;
      if (slot < 64) Cj[w * 64 + slot] = lane * 2 + ((bp >> 1) << 7) + (bp & 1);
      ++slot;
    }
  }
  int cnt = tot > 64 ? 64 : tot;
  int j = Cj[w * 64 + (lane < cnt ? lane : 0)];
  // fp64 rescore (exact; accumulation order identical to R3/R4)
  const float* xTfb = xTf + (((size_t)b) << 11) * CC;
  const float* xi = xTfb + (size_t)irow * CC;
  const float* xj = xTfb + (size_t)j * CC;
  double d0 = 0, d1 = 0, d2 = 0, d3 = 0;
#pragma unroll
  for (int c = 0; c < CC; c += 4) {
    float4 fi = *(const float4*)(xi + c);
    float4 fj = *(const float4*)(xj + c);
    d0 = fma((double)fi.x, (double)fj.x, d0);
    d1 = fma((double)fi.y, (double)fj.y, d1);
    d2 = fma((double)fi.z, (double)fj.z, d2);
    d3 = fma((double)fi.w, (double)fj.w, d3);
  }
  double sc = 2.0 * ((d0 + d1) + (d2 + d3)) - xx[(b << 11) + j];
  // rank via LDS broadcast reads
  Sd[w * 64 + lane] = sc;
  int rank = 0;
#pragma unroll 4
  for (int mm = 0; mm < cnt; ++mm) {
    double sm = Sd[w * 64 + mm];
    int jm = Cj[w * 64 + mm];
    rank += (sm > sc || (sm == sc && jm < j)) ? 1 : 0;
  }
  if (lane < cnt && rank < KK)
    idx[(size_t)((b << 11) + irow) * KK + rank] = j;
}

// ---------------------------------------------------------------------------
// k_stats: per-o sum & sumsq of h = P[gather]+Q (+ optional vmax/vmin emit).
// 1024 blocks x 16 pts for latency hiding (gather-bound).
// ---------------------------------------------------------------------------
__global__ __launch_bounds__(256) void k_stats(const float* __restrict__ P,
                                               const float* __restrict__ Q,
                                               const int* __restrict__ idx,
                                               float* __restrict__ partial,
                                               float* __restrict__ vmaxA,
                                               float* __restrict__ vminA) {
  const int t = threadIdx.x;
  const int o = t & 127, half = t >> 7;
  const int bid = (blockIdx.x & 7) * 128 + (blockIdx.x >> 3);
  float s = 0.f, s2 = 0.f;
  for (int it = 0; it < 8; ++it) {
    int pt = bid * 16 + it * 2 + half;
    int b = pt >> 11;
    float qv = Q[(size_t)pt * OO + o];
    const int* ip = idx + (size_t)pt * KK;
    float vmax = -3.0e38f, vmin = 3.0e38f;
#pragma unroll
    for (int k = 0; k < KK; ++k) {
      float v = P[((size_t)((b << 11) + ip[k])) * OO + o] + qv;
      s += v;
      s2 = fmaf(v, v, s2);
      vmax = fmaxf(vmax, v);
      vmin = fminf(vmin, v);
    }
    if (vmaxA) {
      vmaxA[(size_t)pt * OO + o] = vmax;
      vminA[(size_t)pt * OO + o] = vmin;
    }
  }
  __shared__ float red[512];
  red[t] = s; red[256 + t] = s2;
  __syncthreads();
  if (t < 128) {
    partial[bid * 128 + o]               = red[t] + red[t + 128];
    partial[NPART * 128 + bid * 128 + o] = red[256 + t] + red[256 + t + 128];
  }
}

// ---------------------------------------------------------------------------
// k_fin: finalize BN -> scale/shift per o.
// ---------------------------------------------------------------------------
__global__ __launch_bounds__(256) void k_fin(const float* __restrict__ partial,
                                             const float* __restrict__ gamma,
                                             const float* __restrict__ beta,
                                             float* __restrict__ ss) {
  __shared__ float red[512];
  int t = threadIdx.x;
  int o = t & 127, h = t >> 7;
  float s = 0.f, s2 = 0.f;
  for (int blk = h; blk < NPART; blk += 2) {
    s  += partial[blk * 128 + o];
    s2 += partial[NPART * 128 + blk * 128 + o];
  }
  red[t] = s; red[256 + t] = s2;
  __syncthreads();
  if (t < 128) {
    float st  = red[t] + red[t + 128];
    float s2t = red[256 + t] + red[256 + t + 128];
    float mean = st * (1.0f / M_TOT);
    float var  = s2t * (1.0f / M_TOT) - mean * mean;
    float rs = 1.0f / sqrtf(var + 1e-5f);
    float scale = gamma[t] * rs;
    ss[t] = scale;
    ss[128 + t] = beta[t] - mean * scale;
  }
}

// ---------------------------------------------------------------------------
// k_out: BN affine -> exact GELU -> max over k -> out[b][o][n].
// ---------------------------------------------------------------------------
__global__ __launch_bounds__(256) void k_out(const float* __restrict__ P,
                                             const float* __restrict__ Q,
                                             const int* __restrict__ idx,
                                             const float* __restrict__ ss,
                                             const float* __restrict__ vmaxA,
                                             const float* __restrict__ vminA,
                                             int use_minmax,
                                             float* __restrict__ out) {
  __shared__ float tile[64][OO + 1];
  const int t = threadIdx.x;
  const int o = t & 127, half = t >> 7;
  const int bid = (blockIdx.x & 7) * 32 + (blockIdx.x >> 3);
  const float scale = ss[o], shift = ss[128 + o];
  const int pt0 = bid * 64;
  const int b = pt0 >> 11;
  const float inv_sqrt2 = 0.70710678118654752f;
  for (int it = 0; it < 32; ++it) {
    int pl = it * 2 + half;
    int pt = pt0 + pl;
    float vmax, vmin;
    if (use_minmax) {
      vmax = vmaxA[(size_t)pt * OO + o];
      vmin = vminA[(size_t)pt * OO + o];
    } else {
      float qv = Q[(size_t)pt * OO + o];
      const int* ip = idx + (size_t)pt * KK;
      vmax = -3.0e38f; vmin = 3.0e38f;
#pragma unroll
      for (int k = 0; k < KK; ++k) {
        float v = P[((size_t)((b << 11) + ip[k])) * OO + o] + qv;
        vmax = fmaxf(vmax, v);
        vmin = fminf(vmin, v);
      }
    }
    float ymax, ymin;
    if (scale >= 0.f) { ymax = fmaf(vmax, scale, shift); ymin = fmaf(vmin, scale, shift); }
    else              { ymax = fmaf(vmin, scale, shift); ymin = fmaf(vmax, scale, shift); }
    float g;
    if (ymax > 0.f) {
      g = 0.5f * ymax * (1.0f + erff(ymax * inv_sqrt2));
    } else {
      float g1 = 0.5f * ymax * (1.0f + erff(ymax * inv_sqrt2));
      float g2 = 0.5f * ymin * (1.0f + erff(ymin * inv_sqrt2));
      g = fmaxf(g1, g2);
    }
    tile[pl][o] = g;
  }
  __syncthreads();
  const int n0 = pt0 & (NN - 1);
  for (int rep = 0; rep < 32; ++rep) {
    int oo = rep * 4 + (t >> 6);
    int nn = t & 63;
    out[((size_t)(b * OO + oo) << 11) + n0 + nn] = tile[nn][oo];
  }
}

// ---------------------------------------------------------------------------
extern "C" void kernel_launch(void* const* d_in, const int* in_sizes, int n_in,
                              void* d_out, int out_size, void* d_ws, size_t ws_size,
                              hipStream_t stream) {
  const float* x     = (const float*)d_in[0];
  const float* W     = (const float*)d_in[1];
  const float* gamma = (const float*)d_in[2];
  const float* beta  = (const float*)d_in[3];
  float* out = (float*)d_out;

  const int knn_lds = 16 * NN * 2 + 4096 + 8192;       // 77824 B
  hipFuncSetAttribute((const void*)k_knn,
                      hipFuncAttributeMaxDynamicSharedMemorySize, knn_lds);

  const size_t needA = 131072 + 65536 + 1310720 + (size_t)2 * NPART * 128 * 4 +
                       1024 + 4ull * 8388608;          // ~36.2 MB

  if (ws_size >= needA) {
    // Path A layout
    double* xx   = (double*)d_ws;                      // 131072 B
    float*  xxf  = (float*)(xx + BB * NN);             // 65536 B
    int*    idxp = (int*)(xxf + BB * NN);              // 1310720 B
    float*  part = (float*)(idxp + (size_t)BB * NN * KK); // 1 MB
    float*  ss   = part + 2 * NPART * 128;             // 1024 B
    float*  P    = ss + 256;                           // 8 MB
    float*  Q    = P + (size_t)BB * NN * OO;           // 8 MB
    float*  vmax = Q + (size_t)BB * NN * OO;           // 8 MB
    float*  vmin = vmax + (size_t)BB * NN * OO;        // 8 MB
    ushort* xT   = (ushort*)vmax;                      // 2 MB alias (pre-stats)
    float*  xTf  = vmax + (size_t)BB * NN * (CC / 2);  // 4 MB alias

    hipLaunchKernelGGL(k_pqprep, dim3(BB * NN / 64), dim3(256), 0, stream,
                       x, W, P, Q, xT, xTf, xx, xxf);
    hipLaunchKernelGGL(k_knn, dim3(BB * NN / 16), dim3(1024), knn_lds, stream,
                       xT, xxf, xTf, xx, idxp);
    hipLaunchKernelGGL(k_stats, dim3(NPART), dim3(256), 0, stream,
                       P, Q, idxp, part, vmax, vmin);
    hipLaunchKernelGGL(k_fin, dim3(1), dim3(256), 0, stream, part, gamma, beta, ss);
    hipLaunchKernelGGL(k_out, dim3(BB * NN / 64), dim3(256), 0, stream,
                       P, Q, idxp, ss, vmax, vmin, 1, out);
  } else {
    // Path B layout
    double* xx   = (double*)d_ws;
    int*    idxp = (int*)(xx + BB * NN);
    float*  P    = (float*)(idxp + (size_t)BB * NN * KK);
    float*  Q    = P + (size_t)BB * NN * OO;
    float*  part = Q + (size_t)BB * NN * OO;
    float*  ss   = part + 2 * NPART * 128;
    ushort* xT   = (ushort*)P;
    float*  xTf  = P + (size_t)BB * NN * (CC / 2);
    float*  xxf  = Q;

    hipLaunchKernelGGL(k_prep, dim3(BB * NN / 256), dim3(256), 0, stream,
                       x, xT, xTf, xx, xxf);
    hipLaunchKernelGGL(k_knn, dim3(BB * NN / 16), dim3(1024), knn_lds, stream,
                       xT, xxf, xTf, xx, idxp);
    hipLaunchKernelGGL(k_pq, dim3(BB * NN / 64), dim3(256), 0, stream, x, W, P, Q);
    hipLaunchKernelGGL(k_stats, dim3(NPART), dim3(256), 0, stream,
                       P, Q, idxp, part, (float*)nullptr, (float*)nullptr);
    hipLaunchKernelGGL(k_fin, dim3(1), dim3(256), 0, stream, part, gamma, beta, ss);
    hipLaunchKernelGGL(k_out, dim3(BB * NN / 64), dim3(256), 0, stream,
                       P, Q, idxp, ss, (const float*)nullptr, (const float*)nullptr, 0, out);
  }
}

// Round 7
// 201.934 us; speedup vs baseline: 1.6691x; 1.6691x over previous
//
#include <hip/hip_runtime.h>
#include <math.h>

#define BB 8
#define CC 64
#define NN 2048
#define KK 20
#define OO 128
#define CANDT 40
#define NPART 1024
#define NRED 64            // stage-1 reduction blocks (NPART/NRED = 16 each)
#define M_TOT 327680.0f    // B*N*K

typedef __attribute__((ext_vector_type(8))) __bf16 bf8v;
typedef __attribute__((ext_vector_type(4))) float f32x4;

// ---------------------------------------------------------------------------
// k_pqprep (Path A): P/Q GEMMs + bf16 xT rows + f32 xTf rows + xx/xxf norms.
// ---------------------------------------------------------------------------
__global__ __launch_bounds__(256) void k_pqprep(const float* __restrict__ x,
                                                const float* __restrict__ W,
                                                float* __restrict__ P,
                                                float* __restrict__ Q,
                                                ushort* __restrict__ xT,
                                                float* __restrict__ xTf,
                                                double* __restrict__ xx,
                                                float* __restrict__ xxf) {
  __shared__ float tile[64][OO + 1];               // 33KB
  const int t = threadIdx.x;
  const int jj = t & 63, og = t >> 6;
  const int pt0 = blockIdx.x * 64;
  const int b = pt0 >> 11;
  const int jn = (pt0 & (NN - 1)) + jj;

  float xcol[CC];
#pragma unroll
  for (int c = 0; c < CC; ++c) xcol[c] = x[((size_t)(b * CC + c) << 11) + jn];

  if (og == 0) {                                   // prep outputs (wave 0)
    int i = pt0 + jj;
    ushort* rowp = xT + (size_t)i * CC;
    float* rowf = xTf + (size_t)i * CC;
    double s = 0.0;
#pragma unroll
    for (int c8 = 0; c8 < 8; ++c8) {
      unsigned tmp[8];
#pragma unroll
      for (int e = 0; e < 8; ++e) {
        float v = xcol[c8 * 8 + e];
        double dv = (double)v; s = fma(dv, dv, s);
        __bf16 h = (__bf16)v;
        ushort us; __builtin_memcpy(&us, &h, 2);
        tmp[e] = us;
      }
      uint4 pk;
      pk.x = tmp[0] | (tmp[1] << 16);
      pk.y = tmp[2] | (tmp[3] << 16);
      pk.z = tmp[4] | (tmp[5] << 16);
      pk.w = tmp[6] | (tmp[7] << 16);
      *(uint4*)(rowp + c8 * 8) = pk;
      *(float4*)(rowf + c8 * 8)     = make_float4(xcol[c8*8], xcol[c8*8+1], xcol[c8*8+2], xcol[c8*8+3]);
      *(float4*)(rowf + c8 * 8 + 4) = make_float4(xcol[c8*8+4], xcol[c8*8+5], xcol[c8*8+6], xcol[c8*8+7]);
    }
    xx[i] = s;
    xxf[i] = (float)s;
  }

  for (int oo = 0; oo < 32; ++oo) {
    int o = og * 32 + oo;
    const float* wr = W + (size_t)o * (2 * CC);
    float sp = 0.f;
#pragma unroll
    for (int c = 0; c < CC; ++c) sp = fmaf(wr[c], xcol[c], sp);
    tile[jj][o] = sp;
  }
  __syncthreads();
  for (int it = 0; it < 32; ++it) {
    int r = it * 2 + (t >> 7);
    P[((size_t)(pt0 + r)) * OO + (t & 127)] = tile[r][t & 127];
  }
  __syncthreads();
  for (int oo = 0; oo < 32; ++oo) {
    int o = og * 32 + oo;
    const float* wr = W + (size_t)o * (2 * CC);
    float sq = 0.f;
#pragma unroll
    for (int c = 0; c < CC; ++c) sq = fmaf(wr[CC + c] - wr[c], xcol[c], sq);
    tile[jj][o] = sq;
  }
  __syncthreads();
  for (int it = 0; it < 32; ++it) {
    int r = it * 2 + (t >> 7);
    Q[((size_t)(pt0 + r)) * OO + (t & 127)] = tile[r][t & 127];
  }
}

// ---------------------------------------------------------------------------
// k_prep (Path B fallback): standalone prep pass.
// ---------------------------------------------------------------------------
__global__ __launch_bounds__(256) void k_prep(const float* __restrict__ x,
                                              ushort* __restrict__ xT,
                                              float* __restrict__ xTf,
                                              double* __restrict__ xx,
                                              float* __restrict__ xxf) {
  int i = blockIdx.x * 256 + threadIdx.x;
  int b = i >> 11, n = i & (NN - 1);
  const float* p = x + ((size_t)b * CC) * NN + n;
  ushort* rowp = xT + (size_t)i * CC;
  float* rowf = xTf + (size_t)i * CC;
  double s = 0.0;
#pragma unroll
  for (int c8 = 0; c8 < 8; ++c8) {
    float f[8];
    unsigned tmp[8];
#pragma unroll
    for (int e = 0; e < 8; ++e) {
      float v = p[(size_t)(c8 * 8 + e) * NN];
      f[e] = v;
      double dv = (double)v; s = fma(dv, dv, s);
      __bf16 h = (__bf16)v;
      ushort us; __builtin_memcpy(&us, &h, 2);
      tmp[e] = us;
    }
    uint4 pk;
    pk.x = tmp[0] | (tmp[1] << 16);
    pk.y = tmp[2] | (tmp[3] << 16);
    pk.z = tmp[4] | (tmp[5] << 16);
    pk.w = tmp[6] | (tmp[7] << 16);
    *(uint4*)(rowp + c8 * 8) = pk;
    *(float4*)(rowf + c8 * 8)     = make_float4(f[0], f[1], f[2], f[3]);
    *(float4*)(rowf + c8 * 8 + 4) = make_float4(f[4], f[5], f[6], f[7]);
  }
  xx[i] = s;
  xxf[i] = (float)s;
}

// ---------------------------------------------------------------------------
// k_pq (Path B fallback): P/Q GEMMs only.
// ---------------------------------------------------------------------------
__global__ __launch_bounds__(256) void k_pq(const float* __restrict__ x,
                                            const float* __restrict__ W,
                                            float* __restrict__ P,
                                            float* __restrict__ Q) {
  __shared__ float tile[64][OO + 1];
  const int t = threadIdx.x;
  const int jj = t & 63, og = t >> 6;
  const int pt0 = blockIdx.x * 64;
  const int b = pt0 >> 11;
  const int jn = (pt0 & (NN - 1)) + jj;

  float xcol[CC];
#pragma unroll
  for (int c = 0; c < CC; ++c) xcol[c] = x[((size_t)(b * CC + c) << 11) + jn];

  for (int oo = 0; oo < 32; ++oo) {
    int o = og * 32 + oo;
    const float* wr = W + (size_t)o * (2 * CC);
    float sp = 0.f;
#pragma unroll
    for (int c = 0; c < CC; ++c) sp = fmaf(wr[c], xcol[c], sp);
    tile[jj][o] = sp;
  }
  __syncthreads();
  for (int it = 0; it < 32; ++it) {
    int r = it * 2 + (t >> 7);
    P[((size_t)(pt0 + r)) * OO + (t & 127)] = tile[r][t & 127];
  }
  __syncthreads();
  for (int oo = 0; oo < 32; ++oo) {
    int o = og * 32 + oo;
    const float* wr = W + (size_t)o * (2 * CC);
    float sq = 0.f;
#pragma unroll
    for (int c = 0; c < CC; ++c) sq = fmaf(wr[CC + c] - wr[c], xcol[c], sq);
    tile[jj][o] = sq;
  }
  __syncthreads();
  for (int it = 0; it < 32; ++it) {
    int r = it * 2 + (t >> 7);
    Q[((size_t)(pt0 + r)) * OO + (t & 127)] = tile[r][t & 127];
  }
}

// ---------------------------------------------------------------------------
// k_knn: 16-row tiles, 1024 thr (16 waves), 1 row per wave in selection.
// launch_bounds (1024,4): (1024,8) forced VGPR=32 -> 42MB scratch spill.
// Phase C re-reads keys from LDS to keep VGPR low.
// ---------------------------------------------------------------------------
__global__ __launch_bounds__(1024, 4) void k_knn(
    const ushort* __restrict__ xT, const float* __restrict__ xxf,
    const float* __restrict__ xTf, const double* __restrict__ xx,
    int* __restrict__ idx) {
  extern __shared__ char smem[];
  ushort (*Sb)[NN] = (ushort(*)[NN])smem;          // [16][2048] = 64 KB
  int* Cj = (int*)(smem + 16 * NN * 2);            // [16][64] = 4 KB
  double* Sd = (double*)(smem + 16 * NN * 2 + 4096); // [16][64] = 8 KB
  const int t = threadIdx.x;
  const int w = t >> 6, lane = t & 63;
  const int bidswz = ((blockIdx.x & 7) << 7) + (blockIdx.x >> 3); // batch/XCD
  const int b = bidswz >> 7;
  const int i0 = (bidswz & 127) << 4;
  const int lr16 = lane & 15, kg = lane >> 4;
  const ushort* xTb = xT + (((size_t)b) << 11) * CC;

  // ---- Phase A: MFMA ----
  f32x4 acc[8];
#pragma unroll
  for (int ct = 0; ct < 8; ++ct)
#pragma unroll
    for (int q = 0; q < 4; ++q) acc[ct][q] = 0.f;

  const ushort* Arow = xTb + (size_t)(i0 + lr16) * CC + kg * 8;
  bf8v aF0 = *(const bf8v*)(Arow);
  bf8v aF1 = *(const bf8v*)(Arow + 32);
  const int j0w = w << 7;
#pragma unroll
  for (int ct = 0; ct < 8; ++ct) {
    const ushort* Brow = xTb + (size_t)(j0w + ct * 16 + lr16) * CC + kg * 8;
    bf8v bF0 = *(const bf8v*)(Brow);
    bf8v bF1 = *(const bf8v*)(Brow + 32);
    acc[ct] = __builtin_amdgcn_mfma_f32_16x16x32_bf16(aF0, bF0, acc[ct], 0, 0, 0);
    acc[ct] = __builtin_amdgcn_mfma_f32_16x16x32_bf16(aF1, bF1, acc[ct], 0, 0, 0);
  }

  // ---- Phase B: scores -> bf16 LDS ----
  const float* xxfb = xxf + (b << 11);
#pragma unroll
  for (int ct = 0; ct < 8; ++ct) {
    int j = j0w + ct * 16 + lr16;
    float xv = xxfb[j];
#pragma unroll
    for (int q = 0; q < 4; ++q) {
      int rr = kg * 4 + q;                         // C/D: col=lane&15, row=(lane>>4)*4+q (m89)
      float sv = 2.f * acc[ct][q] - xv;
      __bf16 hb = (__bf16)sv;
      ushort us; __builtin_memcpy(&us, &hb, 2);
      Sb[rr][j] = us;
    }
  }
  __syncthreads();

  // ---- Phase C: wave w owns row i0+w ----
  const int irow = i0 + w;
  unsigned t0 = 0, t1 = 0, t2 = 0, t3 = 0;
#pragma unroll
  for (int g = 0; g < 16; ++g) {
    unsigned raw = *(const unsigned*)(&Sb[w][lane * 2 + g * 128]);
    unsigned r0 = raw & 0xffffu, r1 = raw >> 16;
    unsigned k0 = r0 ^ (0x8000u | ((r0 >> 15) * 0x7FFFu));  // monotone u16
    unsigned k1 = r1 ^ (0x8000u | ((r1 >> 15) * 0x7FFFu));
    unsigned mx, mn;
    mx = k0 > t0 ? k0 : t0; mn = k0 > t0 ? t0 : k0; t0 = mx;
    mx = mn > t1 ? mn : t1; mn = mn > t1 ? t1 : mn; t1 = mx;
    mx = mn > t2 ? mn : t2; mn = mn > t2 ? t2 : mn; t2 = mx;
    t3 = mn > t3 ? mn : t3;
    mx = k1 > t0 ? k1 : t0; mn = k1 > t0 ? t0 : k1; t0 = mx;
    mx = mn > t1 ? mn : t1; mn = mn > t1 ? t1 : mn; t1 = mx;
    mx = mn > t2 ? mn : t2; mn = mn > t2 ? t2 : mn; t2 = mx;
    t3 = mn > t3 ? mn : t3;
  }
  unsigned tau = 0;
  for (int bit = 15; bit >= 0; --bit) {
    unsigned cnd = tau | (1u << bit);
    int tot = __popcll(__ballot(t0 >= cnd)) + __popcll(__ballot(t1 >= cnd)) +
              __popcll(__ballot(t2 >= cnd)) + __popcll(__ballot(t3 >= cnd));
    if (tot >= CANDT) tau = cnd;
  }
  unsigned mask = 0;
#pragma unroll
  for (int g = 0; g < 16; ++g) {
    unsigned raw = *(const unsigned*)(&Sb[w][lane * 2 + g * 128]);
    unsigned r0 = raw & 0xffffu, r1 = raw >> 16;
    unsigned k0 = r0 ^ (0x8000u | ((r0 >> 15) * 0x7FFFu));
    unsigned k1 = r1 ^ (0x8000u | ((r1 >> 15) * 0x7FFFu));
    mask |= (k0 >= tau ? 1u : 0u) << (2 * g);
    mask |= (k1 >= tau ? 1u : 0u) << (2 * g + 1);
  }
  int myc = __popc(mask);
  int pre = myc;
#pragma unroll
  for (int off = 1; off < 64; off <<= 1) {
    int o = __shfl_up(pre, off, 64);
    pre += (lane >= off) ? o : 0;
  }
  int tot = __shfl(pre, 63, 64);
  if (tot > 64) {                                  // cold exact-radix fallback
    tau = 0;
    for (int bit = 15; bit >= 0; --bit) {
      unsigned cnd = tau | (1u << bit);
      int cc = 0;
#pragma unroll
      for (int g = 0; g < 16; ++g) {
        unsigned raw = *(const unsigned*)(&Sb[w][lane * 2 + g * 128]);
        unsigned r0 = raw & 0xffffu, r1 = raw >> 16;
        cc += ((r0 ^ (0x8000u | ((r0 >> 15) * 0x7FFFu))) >= cnd) ? 1 : 0;
        cc += ((r1 ^ (0x8000u | ((r1 >> 15) * 0x7FFFu))) >= cnd) ? 1 : 0;
      }
#pragma unroll
      for (int off = 1; off < 64; off <<= 1) cc += __shfl_xor(cc, off, 64);
      if (cc >= CANDT) tau = cnd;
    }
    mask = 0;
#pragma unroll
    for (int g = 0; g < 16; ++g) {
      unsigned raw = *(const unsigned*)(&Sb[w][lane * 2 + g * 128]);
      unsigned r0 = raw & 0xffffu, r1 = raw >> 16;
      unsigned k0 = r0 ^ (0x8000u | ((r0 >> 15) * 0x7FFFu));
      unsigned k1 = r1 ^ (0x8000u | ((r1 >> 15) * 0x7FFFu));
      mask |= (k0 >= tau ? 1u : 0u) << (2 * g);
      mask |= (k1 >= tau ? 1u : 0u) << (2 * g + 1);
    }
    myc = __popc(mask);
    pre = myc;
#pragma unroll
    for (int off = 1; off < 64; off <<= 1) {
      int o = __shfl_up(pre, off, 64);
      pre += (lane >= off) ? o : 0;
    }
    tot = __shfl(pre, 63, 64);
  }
  {
    int slot = pre - myc;
    unsigned m2 = mask;
    while (m2) {
      int bp = __builtin_ctz(m2); m2 &= m2 - 1;
      if (slot < 64) Cj[w * 64 + slot] = lane * 2 + ((bp >> 1) << 7) + (bp & 1);
      ++slot;
    }
  }
  int cnt = tot > 64 ? 64 : tot;
  int j = Cj[w * 64 + (lane < cnt ? lane : 0)];
  const float* xTfb = xTf + (((size_t)b) << 11) * CC;
  const float* xi = xTfb + (size_t)irow * CC;
  const float* xj = xTfb + (size_t)j * CC;
  double d0 = 0, d1 = 0, d2 = 0, d3 = 0;
#pragma unroll
  for (int c = 0; c < CC; c += 4) {
    float4 fi = *(const float4*)(xi + c);
    float4 fj = *(const float4*)(xj + c);
    d0 = fma((double)fi.x, (double)fj.x, d0);
    d1 = fma((double)fi.y, (double)fj.y, d1);
    d2 = fma((double)fi.z, (double)fj.z, d2);
    d3 = fma((double)fi.w, (double)fj.w, d3);
  }
  double sc = 2.0 * ((d0 + d1) + (d2 + d3)) - xx[(b << 11) + j];
  Sd[w * 64 + lane] = sc;
  int rank = 0;
#pragma unroll 4
  for (int mm = 0; mm < cnt; ++mm) {
    double sm = Sd[w * 64 + mm];
    int jm = Cj[w * 64 + mm];
    rank += (sm > sc || (sm == sc && jm < j)) ? 1 : 0;
  }
  if (lane < cnt && rank < KK)
    idx[(size_t)((b << 11) + irow) * KK + rank] = j;
}

// ---------------------------------------------------------------------------
// k_stats: per-o sum & sumsq of h = P[gather]+Q (+ optional vmax/vmin emit).
// ---------------------------------------------------------------------------
__global__ __launch_bounds__(256) void k_stats(const float* __restrict__ P,
                                               const float* __restrict__ Q,
                                               const int* __restrict__ idx,
                                               float* __restrict__ partial,
                                               float* __restrict__ vmaxA,
                                               float* __restrict__ vminA) {
  const int t = threadIdx.x;
  const int o = t & 127, half = t >> 7;
  const int bid = (blockIdx.x & 7) * 128 + (blockIdx.x >> 3);
  float s = 0.f, s2 = 0.f;
  for (int it = 0; it < 8; ++it) {
    int pt = bid * 16 + it * 2 + half;
    int b = pt >> 11;
    float qv = Q[(size_t)pt * OO + o];
    const int* ip = idx + (size_t)pt * KK;
    float vmax = -3.0e38f, vmin = 3.0e38f;
#pragma unroll
    for (int k = 0; k < KK; ++k) {
      float v = P[((size_t)((b << 11) + ip[k])) * OO + o] + qv;
      s += v;
      s2 = fmaf(v, v, s2);
      vmax = fmaxf(vmax, v);
      vmin = fminf(vmin, v);
    }
    if (vmaxA) {
      vmaxA[(size_t)pt * OO + o] = vmax;
      vminA[(size_t)pt * OO + o] = vmin;
    }
  }
  __shared__ float red[512];
  red[t] = s; red[256 + t] = s2;
  __syncthreads();
  if (t < 128) {
    partial[bid * 128 + o]               = red[t] + red[t + 128];
    partial[NPART * 128 + bid * 128 + o] = red[256 + t] + red[256 + t + 128];
  }
}

// ---------------------------------------------------------------------------
// k_fin1: stage-1 partial reduction. 64 blocks x 256 thr; block r sums
// partial blocks [r*16, r*16+16) -> part2. (R6's single-block k_fin was a
// 1024-iteration serial latency chain = 150us, top dispatch.)
// ---------------------------------------------------------------------------
__global__ __launch_bounds__(256) void k_fin1(const float* __restrict__ partial,
                                              float* __restrict__ part2) {
  __shared__ float red[512];
  const int t = threadIdx.x;
  const int o = t & 127, h = t >> 7;
  const int r = blockIdx.x;
  float s = 0.f, s2 = 0.f;
  for (int q = h; q < NPART / NRED; q += 2) {
    int blk = r * (NPART / NRED) + q;
    s  += partial[blk * 128 + o];
    s2 += partial[NPART * 128 + blk * 128 + o];
  }
  red[t] = s; red[256 + t] = s2;
  __syncthreads();
  if (t < 128) {
    part2[r * 128 + o]              = red[t] + red[t + 128];
    part2[NRED * 128 + r * 128 + o] = red[256 + t] + red[256 + t + 128];
  }
}

// ---------------------------------------------------------------------------
// k_fin2: finalize BN -> scale/shift per o (32 serial iters, 1 block).
// ---------------------------------------------------------------------------
__global__ __launch_bounds__(256) void k_fin2(const float* __restrict__ part2,
                                              const float* __restrict__ gamma,
                                              const float* __restrict__ beta,
                                              float* __restrict__ ss) {
  __shared__ float red[512];
  int t = threadIdx.x;
  int o = t & 127, h = t >> 7;
  float s = 0.f, s2 = 0.f;
  for (int blk = h; blk < NRED; blk += 2) {
    s  += part2[blk * 128 + o];
    s2 += part2[NRED * 128 + blk * 128 + o];
  }
  red[t] = s; red[256 + t] = s2;
  __syncthreads();
  if (t < 128) {
    float st  = red[t] + red[t + 128];
    float s2t = red[256 + t] + red[256 + t + 128];
    float mean = st * (1.0f / M_TOT);
    float var  = s2t * (1.0f / M_TOT) - mean * mean;
    float rs = 1.0f / sqrtf(var + 1e-5f);
    float scale = gamma[t] * rs;
    ss[t] = scale;
    ss[128 + t] = beta[t] - mean * scale;
  }
}

// ---------------------------------------------------------------------------
// k_out: BN affine -> exact GELU -> max over k -> out[b][o][n].
// ---------------------------------------------------------------------------
__global__ __launch_bounds__(256) void k_out(const float* __restrict__ P,
                                             const float* __restrict__ Q,
                                             const int* __restrict__ idx,
                                             const float* __restrict__ ss,
                                             const float* __restrict__ vmaxA,
                                             const float* __restrict__ vminA,
                                             int use_minmax,
                                             float* __restrict__ out) {
  __shared__ float tile[64][OO + 1];
  const int t = threadIdx.x;
  const int o = t & 127, half = t >> 7;
  const int bid = (blockIdx.x & 7) * 32 + (blockIdx.x >> 3);
  const float scale = ss[o], shift = ss[128 + o];
  const int pt0 = bid * 64;
  const int b = pt0 >> 11;
  const float inv_sqrt2 = 0.70710678118654752f;
  for (int it = 0; it < 32; ++it) {
    int pl = it * 2 + half;
    int pt = pt0 + pl;
    float vmax, vmin;
    if (use_minmax) {
      vmax = vmaxA[(size_t)pt * OO + o];
      vmin = vminA[(size_t)pt * OO + o];
    } else {
      float qv = Q[(size_t)pt * OO + o];
      const int* ip = idx + (size_t)pt * KK;
      vmax = -3.0e38f; vmin = 3.0e38f;
#pragma unroll
      for (int k = 0; k < KK; ++k) {
        float v = P[((size_t)((b << 11) + ip[k])) * OO + o] + qv;
        vmax = fmaxf(vmax, v);
        vmin = fminf(vmin, v);
      }
    }
    float ymax, ymin;
    if (scale >= 0.f) { ymax = fmaf(vmax, scale, shift); ymin = fmaf(vmin, scale, shift); }
    else              { ymax = fmaf(vmin, scale, shift); ymin = fmaf(vmax, scale, shift); }
    float g;
    if (ymax > 0.f) {
      g = 0.5f * ymax * (1.0f + erff(ymax * inv_sqrt2));
    } else {
      float g1 = 0.5f * ymax * (1.0f + erff(ymax * inv_sqrt2));
      float g2 = 0.5f * ymin * (1.0f + erff(ymin * inv_sqrt2));
      g = fmaxf(g1, g2);
    }
    tile[pl][o] = g;
  }
  __syncthreads();
  const int n0 = pt0 & (NN - 1);
  for (int rep = 0; rep < 32; ++rep) {
    int oo = rep * 4 + (t >> 6);
    int nn = t & 63;
    out[((size_t)(b * OO + oo) << 11) + n0 + nn] = tile[nn][oo];
  }
}

// ---------------------------------------------------------------------------
extern "C" void kernel_launch(void* const* d_in, const int* in_sizes, int n_in,
                              void* d_out, int out_size, void* d_ws, size_t ws_size,
                              hipStream_t stream) {
  const float* x     = (const float*)d_in[0];
  const float* W     = (const float*)d_in[1];
  const float* gamma = (const float*)d_in[2];
  const float* beta  = (const float*)d_in[3];
  float* out = (float*)d_out;

  const int knn_lds = 16 * NN * 2 + 4096 + 8192;       // 77824 B
  hipFuncSetAttribute((const void*)k_knn,
                      hipFuncAttributeMaxDynamicSharedMemorySize, knn_lds);

  const size_t needA = 131072 + 65536 + 1310720 + (size_t)2 * NPART * 128 * 4 +
                       (size_t)2 * NRED * 128 * 4 + 1024 + 4ull * 8388608;

  if (ws_size >= needA) {
    // Path A layout
    double* xx   = (double*)d_ws;                      // 131072 B
    float*  xxf  = (float*)(xx + BB * NN);             // 65536 B
    int*    idxp = (int*)(xxf + BB * NN);              // 1310720 B
    float*  part = (float*)(idxp + (size_t)BB * NN * KK); // 1 MB
    float*  part2= part + 2 * NPART * 128;             // 64 KB
    float*  ss   = part2 + 2 * NRED * 128;             // 1024 B
    float*  P    = ss + 256;                           // 8 MB
    float*  Q    = P + (size_t)BB * NN * OO;           // 8 MB
    float*  vmax = Q + (size_t)BB * NN * OO;           // 8 MB
    float*  vmin = vmax + (size_t)BB * NN * OO;        // 8 MB
    ushort* xT   = (ushort*)vmax;                      // 2 MB alias (pre-stats)
    float*  xTf  = vmax + (size_t)BB * NN * (CC / 2);  // 4 MB alias

    hipLaunchKernelGGL(k_pqprep, dim3(BB * NN / 64), dim3(256), 0, stream,
                       x, W, P, Q, xT, xTf, xx, xxf);
    hipLaunchKernelGGL(k_knn, dim3(BB * NN / 16), dim3(1024), knn_lds, stream,
                       xT, xxf, xTf, xx, idxp);
    hipLaunchKernelGGL(k_stats, dim3(NPART), dim3(256), 0, stream,
                       P, Q, idxp, part, vmax, vmin);
    hipLaunchKernelGGL(k_fin1, dim3(NRED), dim3(256), 0, stream, part, part2);
    hipLaunchKernelGGL(k_fin2, dim3(1), dim3(256), 0, stream, part2, gamma, beta, ss);
    hipLaunchKernelGGL(k_out, dim3(BB * NN / 64), dim3(256), 0, stream,
                       P, Q, idxp, ss, vmax, vmin, 1, out);
  } else {
    // Path B layout
    double* xx   = (double*)d_ws;
    int*    idxp = (int*)(xx + BB * NN);
    float*  P    = (float*)(idxp + (size_t)BB * NN * KK);
    float*  Q    = P + (size_t)BB * NN * OO;
    float*  part = Q + (size_t)BB * NN * OO;
    float*  part2= part + 2 * NPART * 128;
    float*  ss   = part2 + 2 * NRED * 128;
    ushort* xT   = (ushort*)P;
    float*  xTf  = P + (size_t)BB * NN * (CC / 2);
    float*  xxf  = Q;

    hipLaunchKernelGGL(k_prep, dim3(BB * NN / 256), dim3(256), 0, stream,
                       x, xT, xTf, xx, xxf);
    hipLaunchKernelGGL(k_knn, dim3(BB * NN / 16), dim3(1024), knn_lds, stream,
                       xT, xxf, xTf, xx, idxp);
    hipLaunchKernelGGL(k_pq, dim3(BB * NN / 64), dim3(256), 0, stream, x, W, P, Q);
    hipLaunchKernelGGL(k_stats, dim3(NPART), dim3(256), 0, stream,
                       P, Q, idxp, part, (float*)nullptr, (float*)nullptr);
    hipLaunchKernelGGL(k_fin1, dim3(NRED), dim3(256), 0, stream, part, part2);
    hipLaunchKernelGGL(k_fin2, dim3(1), dim3(256), 0, stream, part2, gamma, beta, ss);
    hipLaunchKernelGGL(k_out, dim3(BB * NN / 64), dim3(256), 0, stream,
                       P, Q, idxp, ss, (const float*)nullptr, (const float*)nullptr, 0, out);
  }
}